// Round 18
// baseline (81.549 us; speedup 1.0000x reference)
//
#include <hip/hip_runtime.h>
#include <stdint.h>

// Problem constants
#define D_DIM 512
#define B_ROWS 4096
#define N_ROWS 8192
// (1/TEMPERATURE) * log2(e) : exp(x/T) == exp2(x * SCALE_L2E)
#define SCALE_L2E 14.426950408889634f

#define NST 16                      // K steps of 32
// 128-row cells: 64 per side; unordered pairs (a<=b): 2080 = 8*260.
// Supertiled: supers of 8 cells -> 28 off-diag SPs x 64 + 8 diag SPs x 36.
#define NBLK 2080

typedef __attribute__((ext_vector_type(4))) float f32x4;
typedef long f8x8;                  // 8 fp8 bytes = 2 VGPRs (one K=32 MFMA operand)

using gas1_t = const __attribute__((address_space(1))) void;
using las3_t = __attribute__((address_space(3))) void;
#define GLOAD16(g, l) __builtin_amdgcn_global_load_lds((gas1_t*)(g), (las3_t*)(l), 16, 0, 0)

// ---------------- K1: normalize rows -> fp8 e4m3 Zn ([hc][row][32B] planes), fp32 pos;
//                     also zeros the rowsum accumulator (blocks 0..7) ----------------------
__global__ __launch_bounds__(256) void k_normalize(const float* __restrict__ zi,
                                                   const float* __restrict__ zj,
                                                   unsigned char* __restrict__ Zn,
                                                   float* __restrict__ pos,
                                                   float* __restrict__ rowsum_g) {
    const int t = threadIdx.x;
    if (blockIdx.x < 8) {  // zero rowsum (runs before k_gemm in-stream; no race)
        float4 z = {0.0f, 0.0f, 0.0f, 0.0f};
        *(float4*)(rowsum_g + blockIdx.x * 1024 + t * 4) = z;
    }
    const int lane = t & 63;
    const int i = blockIdx.x * 4 + (t >> 6);
    const float* pa = zi + (size_t)i * D_DIM + lane * 8;
    const float* pb = zj + (size_t)i * D_DIM + lane * 8;
    const float4 a0 = *(const float4*)pa;
    const float4 a1 = *(const float4*)(pa + 4);
    const float4 b0 = *(const float4*)pb;
    const float4 b1 = *(const float4*)(pb + 4);
    float ssi = a0.x*a0.x + a0.y*a0.y + a0.z*a0.z + a0.w*a0.w
              + a1.x*a1.x + a1.y*a1.y + a1.z*a1.z + a1.w*a1.w;
    float ssj = b0.x*b0.x + b0.y*b0.y + b0.z*b0.z + b0.w*b0.w
              + b1.x*b1.x + b1.y*b1.y + b1.z*b1.z + b1.w*b1.w;
    float dt  = a0.x*b0.x + a0.y*b0.y + a0.z*b0.z + a0.w*b0.w
              + a1.x*b1.x + a1.y*b1.y + a1.z*b1.z + a1.w*b1.w;
    #pragma unroll
    for (int off = 1; off < 64; off <<= 1) {
        ssi += __shfl_xor(ssi, off);
        ssj += __shfl_xor(ssj, off);
        dt  += __shfl_xor(dt,  off);
    }
    const float si = 1.0f / fmaxf(sqrtf(ssi), 1e-12f);
    const float sj = 1.0f / fmaxf(sqrtf(ssj), 1e-12f);
    uint2 pi8, pj8;
    {
        int w0 = 0, w1 = 0;
        w0 = __builtin_amdgcn_cvt_pk_fp8_f32(a0.x * si, a0.y * si, w0, false);
        w0 = __builtin_amdgcn_cvt_pk_fp8_f32(a0.z * si, a0.w * si, w0, true);
        w1 = __builtin_amdgcn_cvt_pk_fp8_f32(a1.x * si, a1.y * si, w1, false);
        w1 = __builtin_amdgcn_cvt_pk_fp8_f32(a1.z * si, a1.w * si, w1, true);
        pi8.x = (unsigned)w0; pi8.y = (unsigned)w1;
        w0 = 0; w1 = 0;
        w0 = __builtin_amdgcn_cvt_pk_fp8_f32(b0.x * sj, b0.y * sj, w0, false);
        w0 = __builtin_amdgcn_cvt_pk_fp8_f32(b0.z * sj, b0.w * sj, w0, true);
        w1 = __builtin_amdgcn_cvt_pk_fp8_f32(b1.x * sj, b1.y * sj, w1, false);
        w1 = __builtin_amdgcn_cvt_pk_fp8_f32(b1.z * sj, b1.w * sj, w1, true);
        pj8.x = (unsigned)w0; pj8.y = (unsigned)w1;
    }
    // lane covers k = lane*8..+7 -> hc = lane>>2, 8B-seg = lane&3
    const size_t PLANE = (size_t)N_ROWS * 32;  // bytes per hc-plane
    const size_t off0  = (size_t)(lane >> 2) * PLANE + (lane & 3) * 8;
    *(uint2*)(Zn + off0 + (size_t)i * 32) = pi8;
    *(uint2*)(Zn + off0 + (size_t)(B_ROWS + i) * 32) = pj8;
    if (lane == 0) pos[i] = 20.0f * dt * si * sj;  // positive logit counted twice: 2*dot/T
}

// ---------------- K2: symmetric fused S = Zn·Zn^T (fp8 MFMA) + per-row sum(exp(S/T)) ------
// 128x128 cell (a<=b) per 4-wave block (2x2 quadrants of 64x64). LDS staging shares panel
// loads across waves: 128 global lines/block-step vs 256 direct (2x line reduction -> the
// r10-r17 MSHR wall at 0.29 lines/cy/CU moves from ~49us to ~24us). 8-slot LDS ring at
// K=32 granularity (64 KiB -> 2 blocks/CU), prologue 5 slots ahead (~2000cy lookahead >>
// L2 latency -- fixes r6's 390cy-lookahead failure). Per step: counted vmcnt (exact, never
// over-drains) -> barrier -> stage s+5 -> ds_read frags -> 16 MFMA.
__global__ __launch_bounds__(256, 2) void k_gemm_lse(const unsigned char* __restrict__ Zn,
                                                     float* __restrict__ rowsum_g) {
    __shared__ __align__(16) char lds[8 * 8192];   // 8 ring slots: [A 4KB][B 4KB]
    const int t    = threadIdx.x;
    const int lane = t & 63;
    const int w    = t >> 6;
    const int wm   = w >> 1, wn = w & 1;           // 2 x 2 quadrant grid
    const int l15  = lane & 15, lhi = lane >> 4;

    // XCD-aware swizzle (bijective: NBLK % 8 == 0), then supertiled cell decode
    int g = (blockIdx.x & 7) * (NBLK / 8) + (blockIdx.x >> 3);
    int SI = 0, SJ = 0;
    {
        bool found = false;
        for (SI = 0; SI < 8 && !found; ++SI) {
            for (SJ = SI; SJ < 8; ++SJ) {
                const int sz = (SI == SJ) ? 36 : 64;
                if (g < sz) { found = true; break; }
                g -= sz;
            }
        }
        --SI;
    }
    int di, dj;
    if (SI == SJ) {
        di = 0;
        while (g >= 8 - di) { g -= 8 - di; ++di; }
        dj = di + g;
    } else {
        di = g >> 3; dj = g & 7;
    }
    const int a = SI * 8 + di, b = SJ * 8 + dj;
    const bool dg = (a == b);
    const int rowPanel = a * 128, colPanel = b * 128;
    // quadrant write mode: 0=skip (dg lower dup), 1=diag-masked rows, 2=full rows+cols
    const int mode = !dg ? 2 : (wm == wn ? 1 : (wm == 0 ? 2 : 0));
    const int rowBw = rowPanel + wm * 64;   // wave's 64 output rows
    const int colBw = colPanel + wn * 64;   // wave's 64 output cols

    const char* Zb = (const char*)Zn;
    const size_t PLANE = (size_t)N_ROWS * 32;  // bytes per hc-plane

    // staging source: thread t fetches rows rowPanel + t/2, 16B half t&1 (4KB contiguous)
    const char* srcA = Zb + ((size_t)(rowPanel + (t >> 1))) * 32 + (t & 1) * 16;
    const char* srcB = Zb + ((size_t)(colPanel + (t >> 1))) * 32 + (t & 1) * 16;
    char* ldsb = (char*)lds;

#define STAGE(k)                                                                    \
    do {                                                                            \
        const size_t _o = (size_t)(k) * PLANE;                                      \
        char* _d = ldsb + (((k) & 7) * 8192) + t * 16;                              \
        GLOAD16(srcA + _o, _d);                                                     \
        GLOAD16(srcB + _o, _d + 4096);                                              \
    } while (0)

    // fragment read bases (step-invariant)
    const int aBase = (wm * 64 + l15) * 32 + lhi * 8;
    const int bBase = 4096 + (wn * 64 + l15) * 32 + lhi * 8;

    f32x4 acc[4][4];
    #pragma unroll
    for (int x = 0; x < 4; ++x)
        #pragma unroll
        for (int y = 0; y < 4; ++y)
            #pragma unroll
            for (int q = 0; q < 4; ++q) acc[x][y][q] = 0.0f;

#define COMPUTE(k)                                                                  \
    do {                                                                            \
        const char* sb = (const char*)lds + (((k) & 7) * 8192);                     \
        f8x8 af[4], bg[4];                                                          \
        _Pragma("unroll")                                                           \
        for (int mi = 0; mi < 4; ++mi) af[mi] = *(const f8x8*)(sb + aBase + mi * 512); \
        _Pragma("unroll")                                                           \
        for (int ni = 0; ni < 4; ++ni) bg[ni] = *(const f8x8*)(sb + bBase + ni * 512); \
        __builtin_amdgcn_s_setprio(1);                                              \
        _Pragma("unroll")                                                           \
        for (int mi = 0; mi < 4; ++mi)                                              \
            _Pragma("unroll")                                                       \
            for (int ni = 0; ni < 4; ++ni)                                          \
                acc[mi][ni] = __builtin_amdgcn_mfma_f32_16x16x32_fp8_fp8(           \
                    af[mi], bg[ni], acc[mi][ni], 0, 0, 0);                          \
        __builtin_amdgcn_s_setprio(0);                                              \
    } while (0)

// step: [my stage(s) landed: vmcnt] -> [everyone's landed: barrier] -> issue stage(s+5)
// -> read frags of slot s -> MFMA. W = 2 * min(4, 15-s) (2 loads per in-flight stage).
#define STEP(s, W)                                                                  \
    do {                                                                            \
        asm volatile("s_waitcnt vmcnt(" W ")" ::: "memory");                        \
        __builtin_amdgcn_sched_barrier(0);                                          \
        __builtin_amdgcn_s_barrier();                                               \
        __builtin_amdgcn_sched_barrier(0);                                          \
        if ((s) + 5 < NST) STAGE((s) + 5);                                          \
        COMPUTE(s);                                                                 \
    } while (0)

    // prologue: 5 slots in flight (10 loads/thread)
    STAGE(0); STAGE(1); STAGE(2); STAGE(3); STAGE(4);

    STEP(0, "8");  STEP(1, "8");  STEP(2, "8");  STEP(3, "8");
    STEP(4, "8");  STEP(5, "8");  STEP(6, "8");  STEP(7, "8");
    STEP(8, "8");  STEP(9, "8");  STEP(10, "8"); STEP(11, "8");
    STEP(12, "6"); STEP(13, "4"); STEP(14, "2"); STEP(15, "0");

    // epilogue: e = exp2(S * 10*log2e); C/D layout: col=lane&15, row=(lane>>4)*4+reg
    if (mode != 0) {
        float colsum[4] = {0.0f, 0.0f, 0.0f, 0.0f};
        #pragma unroll
        for (int mi = 0; mi < 4; ++mi) {
            const int growb = rowBw + mi * 16 + lhi * 4;
            float rs[4] = {0.0f, 0.0f, 0.0f, 0.0f};
            if (mode == 1) {
                #pragma unroll
                for (int ni = 0; ni < 4; ++ni) {
                    const int gcol = colBw + ni * 16 + l15;
                    #pragma unroll
                    for (int r = 0; r < 4; ++r) {
                        float arg = acc[mi][ni][r] * SCALE_L2E;
                        if (growb + r == gcol) arg = -1e30f;  // diagonal mask -> exp2 = 0
                        rs[r] += exp2f(arg);
                    }
                }
            } else {
                #pragma unroll
                for (int ni = 0; ni < 4; ++ni)
                    #pragma unroll
                    for (int r = 0; r < 4; ++r) {
                        const float e = exp2f(acc[mi][ni][r] * SCALE_L2E);
                        rs[r] += e;
                        colsum[ni] += e;
                    }
            }
            // row sums: reduce the 16 lanes sharing lhi; one atomic per (mi, r)
            #pragma unroll
            for (int r = 0; r < 4; ++r) {
                float v = rs[r];
                v += __shfl_xor(v, 1);
                v += __shfl_xor(v, 2);
                v += __shfl_xor(v, 4);
                v += __shfl_xor(v, 8);
                if (l15 == 0) atomicAdd(&rowsum_g[growb + r], v);
            }
        }
        if (mode == 2) {
            // column sums (symmetry): reduce across lhi groups; lanes lhi==0 hold col l15
            #pragma unroll
            for (int ni = 0; ni < 4; ++ni) {
                float c = colsum[ni];
                c += __shfl_xor(c, 16);
                c += __shfl_xor(c, 32);
                if (lhi == 0)
                    atomicAdd(&rowsum_g[colBw + ni * 16 + l15], c);
            }
        }
    }
#undef STAGE
#undef COMPUTE
#undef STEP
}

// ---------------- K3: loss = mean(ln(rowsum)) - mean(pos), single block ----------------
__global__ __launch_bounds__(1024) void k_finalize(const float* __restrict__ rowsum_g,
                                                   const float* __restrict__ pos,
                                                   float* __restrict__ out) {
    const int t = threadIdx.x;
    float l = 0.0f, p = 0.0f;
    #pragma unroll
    for (int q = 0; q < N_ROWS / 1024; ++q) l += logf(rowsum_g[t + q * 1024]);
    #pragma unroll
    for (int q = 0; q < B_ROWS / 1024; ++q) p += pos[t + q * 1024];
    #pragma unroll
    for (int off = 1; off < 64; off <<= 1) {
        l += __shfl_xor(l, off);
        p += __shfl_xor(p, off);
    }
    __shared__ float red[2][16];
    if ((t & 63) == 0) { red[0][t >> 6] = l; red[1][t >> 6] = p; }
    __syncthreads();
    if (t == 0) {
        float L = 0.0f, P = 0.0f;
        #pragma unroll
        for (int q = 0; q < 16; ++q) { L += red[0][q]; P += red[1][q]; }
        out[0] = (L - P) * (1.0f / (float)N_ROWS);
    }
}

extern "C" void kernel_launch(void* const* d_in, const int* in_sizes, int n_in,
                              void* d_out, int out_size, void* d_ws, size_t ws_size,
                              hipStream_t stream) {
    (void)in_sizes; (void)n_in; (void)out_size; (void)ws_size;
    const float* zi = (const float*)d_in[0];
    const float* zj = (const float*)d_in[1];

    // workspace layout
    const size_t ZN_BYTES = (size_t)N_ROWS * D_DIM;  // 4 MiB fp8 (hc-tiled)
    unsigned char* Zn     = (unsigned char*)d_ws;
    float* rowsum_g       = (float*)((char*)d_ws + ZN_BYTES);              // 8192 f32
    float* pos            = (float*)((char*)d_ws + ZN_BYTES + N_ROWS * 4); // 4096 f32

    k_normalize<<<B_ROWS / 4, 256, 0, stream>>>(zi, zj, Zn, pos, rowsum_g);
    k_gemm_lse<<<NBLK, 256, 0, stream>>>(Zn, rowsum_g);
    k_finalize<<<1, 1024, 0, stream>>>(rowsum_g, pos, (float*)d_out);
}

// Round 19
// 55.416 us; speedup vs baseline: 1.4716x; 1.4716x over previous
//
#include <hip/hip_runtime.h>
#include <stdint.h>

// Problem constants
#define D_DIM 512
#define B_ROWS 4096
#define N_ROWS 8192
// (1/TEMPERATURE) * log2(e) : exp(x/T) == exp2(x * SCALE_L2E)
#define SCALE_L2E 14.426950408889634f

#define NST 16                      // K steps of 32
// 128-row cells: 64 per side; unordered pairs (a<=b): 2080 = 8*260.
// Supertiled: supers of 8 cells -> 28 off-diag SPs x 64 + 8 diag SPs x 36.
#define NBLK 2080

typedef __attribute__((ext_vector_type(4))) float f32x4;
typedef long f8x8;                  // 8 fp8 bytes = 2 VGPRs (one K=32 MFMA operand)

using gas1_t = const __attribute__((address_space(1))) void;
using las3_t = __attribute__((address_space(3))) void;
#define GLOAD16(g, l) __builtin_amdgcn_global_load_lds((gas1_t*)(g), (las3_t*)(l), 16, 0, 0)

// ---------------- K1: normalize rows -> fp8 e4m3 Zn ([hc][row][32B] planes), fp32 pos;
//                     also zeros the rowsum accumulator (blocks 0..7) ----------------------
__global__ __launch_bounds__(256) void k_normalize(const float* __restrict__ zi,
                                                   const float* __restrict__ zj,
                                                   unsigned char* __restrict__ Zn,
                                                   float* __restrict__ pos,
                                                   float* __restrict__ rowsum_g) {
    const int t = threadIdx.x;
    if (blockIdx.x < 8) {  // zero rowsum (runs before k_gemm in-stream; no race)
        float4 z = {0.0f, 0.0f, 0.0f, 0.0f};
        *(float4*)(rowsum_g + blockIdx.x * 1024 + t * 4) = z;
    }
    const int lane = t & 63;
    const int i = blockIdx.x * 4 + (t >> 6);
    const float* pa = zi + (size_t)i * D_DIM + lane * 8;
    const float* pb = zj + (size_t)i * D_DIM + lane * 8;
    const float4 a0 = *(const float4*)pa;
    const float4 a1 = *(const float4*)(pa + 4);
    const float4 b0 = *(const float4*)pb;
    const float4 b1 = *(const float4*)(pb + 4);
    float ssi = a0.x*a0.x + a0.y*a0.y + a0.z*a0.z + a0.w*a0.w
              + a1.x*a1.x + a1.y*a1.y + a1.z*a1.z + a1.w*a1.w;
    float ssj = b0.x*b0.x + b0.y*b0.y + b0.z*b0.z + b0.w*b0.w
              + b1.x*b1.x + b1.y*b1.y + b1.z*b1.z + b1.w*b1.w;
    float dt  = a0.x*b0.x + a0.y*b0.y + a0.z*b0.z + a0.w*b0.w
              + a1.x*b1.x + a1.y*b1.y + a1.z*b1.z + a1.w*b1.w;
    #pragma unroll
    for (int off = 1; off < 64; off <<= 1) {
        ssi += __shfl_xor(ssi, off);
        ssj += __shfl_xor(ssj, off);
        dt  += __shfl_xor(dt,  off);
    }
    const float si = 1.0f / fmaxf(sqrtf(ssi), 1e-12f);
    const float sj = 1.0f / fmaxf(sqrtf(ssj), 1e-12f);
    uint2 pi8, pj8;
    {
        int w0 = 0, w1 = 0;
        w0 = __builtin_amdgcn_cvt_pk_fp8_f32(a0.x * si, a0.y * si, w0, false);
        w0 = __builtin_amdgcn_cvt_pk_fp8_f32(a0.z * si, a0.w * si, w0, true);
        w1 = __builtin_amdgcn_cvt_pk_fp8_f32(a1.x * si, a1.y * si, w1, false);
        w1 = __builtin_amdgcn_cvt_pk_fp8_f32(a1.z * si, a1.w * si, w1, true);
        pi8.x = (unsigned)w0; pi8.y = (unsigned)w1;
        w0 = 0; w1 = 0;
        w0 = __builtin_amdgcn_cvt_pk_fp8_f32(b0.x * sj, b0.y * sj, w0, false);
        w0 = __builtin_amdgcn_cvt_pk_fp8_f32(b0.z * sj, b0.w * sj, w0, true);
        w1 = __builtin_amdgcn_cvt_pk_fp8_f32(b1.x * sj, b1.y * sj, w1, false);
        w1 = __builtin_amdgcn_cvt_pk_fp8_f32(b1.z * sj, b1.w * sj, w1, true);
        pj8.x = (unsigned)w0; pj8.y = (unsigned)w1;
    }
    // lane covers k = lane*8..+7 -> hc = lane>>2, 8B-seg = lane&3
    const size_t PLANE = (size_t)N_ROWS * 32;  // bytes per hc-plane
    const size_t off0  = (size_t)(lane >> 2) * PLANE + (lane & 3) * 8;
    *(uint2*)(Zn + off0 + (size_t)i * 32) = pi8;
    *(uint2*)(Zn + off0 + (size_t)(B_ROWS + i) * 32) = pj8;
    if (lane == 0) pos[i] = 20.0f * dt * si * sj;  // positive logit counted twice: 2*dot/T
}

// ---------------- K2: symmetric fused S = Zn·Zn^T (fp8 MFMA) + per-row sum(exp(S/T)) ------
// 128x128 cell (a<=b) per 4-wave block (2x2 quadrants of 64x64). LDS staging shares panel
// loads across waves (2x unique-line reduction vs direct loads). 6-slot LDS ring at K=32
// granularity (48 KiB -> 3 blocks/CU), 4-ahead lookahead (~1300cy >> L2 latency), counted
// vmcnt (never over-drains). CONFLICT-FREE chunk-swizzled slot layout: 16B chunk of
// (row, half) at chunk index L = (row&15) + ((row>>4)*2 + half)*16 -> frag ds_read_b64s
// land exactly 2 dwords/bank per 32-lane phase (free). Staging keeps linear gload_lds dest
// (t*16) with the inverse-permuted global source (both-sides rule).
__global__ __launch_bounds__(256, 3) void k_gemm_lse(const unsigned char* __restrict__ Zn,
                                                     float* __restrict__ rowsum_g) {
    __shared__ __align__(16) char lds[6 * 8192];   // 6 ring slots: [A 4KB][B 4KB]
    const int t    = threadIdx.x;
    const int lane = t & 63;
    const int w    = t >> 6;
    const int wm   = w >> 1, wn = w & 1;           // 2 x 2 quadrant grid
    const int l15  = lane & 15, lhi = lane >> 4;

    // XCD-aware swizzle (bijective: NBLK % 8 == 0), then supertiled cell decode
    int g = (blockIdx.x & 7) * (NBLK / 8) + (blockIdx.x >> 3);
    int SI = 0, SJ = 0;
    {
        bool found = false;
        for (SI = 0; SI < 8 && !found; ++SI) {
            for (SJ = SI; SJ < 8; ++SJ) {
                const int sz = (SI == SJ) ? 36 : 64;
                if (g < sz) { found = true; break; }
                g -= sz;
            }
        }
        --SI;
    }
    int di, dj;
    if (SI == SJ) {
        di = 0;
        while (g >= 8 - di) { g -= 8 - di; ++di; }
        dj = di + g;
    } else {
        di = g >> 3; dj = g & 7;
    }
    const int a = SI * 8 + di, b = SJ * 8 + dj;
    const bool dg = (a == b);
    const int rowPanel = a * 128, colPanel = b * 128;
    // quadrant write mode: 0=skip (dg lower dup), 1=diag-masked rows, 2=full rows+cols
    const int mode = !dg ? 2 : (wm == wn ? 1 : (wm == 0 ? 2 : 0));
    const int rowBw = rowPanel + wm * 64;   // wave's 64 output rows
    const int colBw = colPanel + wn * 64;   // wave's 64 output cols

    const char* Zb = (const char*)Zn;
    const size_t PLANE = (size_t)N_ROWS * 32;  // bytes per hc-plane

    // staging: LDS chunk c = t holds global (row, half) with row = (t>>5)*16 + (t&15),
    // half = (t>>4)&1  [inverse of L]. Source still coalesced (32 threads = 8 full lines).
    const int srow  = (t >> 5) * 16 + (t & 15);
    const int shalf = (t >> 4) & 1;
    const char* srcA = Zb + ((size_t)(rowPanel + srow)) * 32 + shalf * 16;
    const char* srcB = Zb + ((size_t)(colPanel + srow)) * 32 + shalf * 16;
    char* ldsb = (char*)lds;

#define STAGE(k)                                                                    \
    do {                                                                            \
        const size_t _o = (size_t)(k) * PLANE;                                      \
        char* _d = ldsb + (((k) % 6) * 8192) + t * 16;                              \
        GLOAD16(srcA + _o, _d);                                                     \
        GLOAD16(srcB + _o, _d + 4096);                                              \
    } while (0)

    // frag read bases: lane (lhi,l15), frag mi: byte =
    //   l15*16 + (lhi&1)*8 + (lhi>>1)*256 + (wm*4+mi)*512   [A; B at +4096 with wn]
    const int aBase = l15 * 16 + (lhi & 1) * 8 + (lhi >> 1) * 256 + wm * 2048;
    const int bBase = 4096 + l15 * 16 + (lhi & 1) * 8 + (lhi >> 1) * 256 + wn * 2048;

    f32x4 acc[4][4];
    #pragma unroll
    for (int x = 0; x < 4; ++x)
        #pragma unroll
        for (int y = 0; y < 4; ++y)
            #pragma unroll
            for (int q = 0; q < 4; ++q) acc[x][y][q] = 0.0f;

#define COMPUTE(k)                                                                  \
    do {                                                                            \
        const char* sb = (const char*)lds + (((k) % 6) * 8192);                     \
        f8x8 af[4], bg[4];                                                          \
        _Pragma("unroll")                                                           \
        for (int mi = 0; mi < 4; ++mi) af[mi] = *(const f8x8*)(sb + aBase + mi * 512); \
        _Pragma("unroll")                                                           \
        for (int ni = 0; ni < 4; ++ni) bg[ni] = *(const f8x8*)(sb + bBase + ni * 512); \
        __builtin_amdgcn_s_setprio(1);                                              \
        _Pragma("unroll")                                                           \
        for (int mi = 0; mi < 4; ++mi)                                              \
            _Pragma("unroll")                                                       \
            for (int ni = 0; ni < 4; ++ni)                                          \
                acc[mi][ni] = __builtin_amdgcn_mfma_f32_16x16x32_fp8_fp8(           \
                    af[mi], bg[ni], acc[mi][ni], 0, 0, 0);                          \
        __builtin_amdgcn_s_setprio(0);                                              \
    } while (0)

// step: [my stage(s) landed: vmcnt] -> [everyone's: barrier] -> issue stage(s+4)
// -> read frags of slot s -> MFMA. Steady W = 2*(4-1) = 6 (2 loads per in-flight stage).
#define STEP(s, W)                                                                  \
    do {                                                                            \
        asm volatile("s_waitcnt vmcnt(" W ")" ::: "memory");                        \
        __builtin_amdgcn_sched_barrier(0);                                          \
        __builtin_amdgcn_s_barrier();                                               \
        __builtin_amdgcn_sched_barrier(0);                                          \
        if ((s) + 4 < NST) STAGE((s) + 4);                                          \
        COMPUTE(s);                                                                 \
    } while (0)

    // prologue: 4 slots in flight (8 loads/thread)
    STAGE(0); STAGE(1); STAGE(2); STAGE(3);

    STEP(0, "6");  STEP(1, "6");  STEP(2, "6");  STEP(3, "6");
    STEP(4, "6");  STEP(5, "6");  STEP(6, "6");  STEP(7, "6");
    STEP(8, "6");  STEP(9, "6");  STEP(10, "6"); STEP(11, "6");
    STEP(12, "6"); STEP(13, "4"); STEP(14, "2"); STEP(15, "0");

    // epilogue: e = exp2(S * 10*log2e); C/D layout: col=lane&15, row=(lane>>4)*4+reg
    if (mode != 0) {
        float colsum[4] = {0.0f, 0.0f, 0.0f, 0.0f};
        #pragma unroll
        for (int mi = 0; mi < 4; ++mi) {
            const int growb = rowBw + mi * 16 + lhi * 4;
            float rs[4] = {0.0f, 0.0f, 0.0f, 0.0f};
            if (mode == 1) {
                #pragma unroll
                for (int ni = 0; ni < 4; ++ni) {
                    const int gcol = colBw + ni * 16 + l15;
                    #pragma unroll
                    for (int r = 0; r < 4; ++r) {
                        float arg = acc[mi][ni][r] * SCALE_L2E;
                        if (growb + r == gcol) arg = -1e30f;  // diagonal mask -> exp2 = 0
                        rs[r] += exp2f(arg);
                    }
                }
            } else {
                #pragma unroll
                for (int ni = 0; ni < 4; ++ni)
                    #pragma unroll
                    for (int r = 0; r < 4; ++r) {
                        const float e = exp2f(acc[mi][ni][r] * SCALE_L2E);
                        rs[r] += e;
                        colsum[ni] += e;
                    }
            }
            // row sums: reduce the 16 lanes sharing lhi; one atomic per (mi, r)
            #pragma unroll
            for (int r = 0; r < 4; ++r) {
                float v = rs[r];
                v += __shfl_xor(v, 1);
                v += __shfl_xor(v, 2);
                v += __shfl_xor(v, 4);
                v += __shfl_xor(v, 8);
                if (l15 == 0) atomicAdd(&rowsum_g[growb + r], v);
            }
        }
        if (mode == 2) {
            // column sums (symmetry): reduce across lhi groups; lanes lhi==0 hold col l15
            #pragma unroll
            for (int ni = 0; ni < 4; ++ni) {
                float c = colsum[ni];
                c += __shfl_xor(c, 16);
                c += __shfl_xor(c, 32);
                if (lhi == 0)
                    atomicAdd(&rowsum_g[colBw + ni * 16 + l15], c);
            }
        }
    }
#undef STAGE
#undef COMPUTE
#undef STEP
}

// ---------------- K3: loss = mean(ln(rowsum)) - mean(pos), single block ----------------
__global__ __launch_bounds__(1024) void k_finalize(const float* __restrict__ rowsum_g,
                                                   const float* __restrict__ pos,
                                                   float* __restrict__ out) {
    const int t = threadIdx.x;
    float l = 0.0f, p = 0.0f;
    #pragma unroll
    for (int q = 0; q < N_ROWS / 1024; ++q) l += logf(rowsum_g[t + q * 1024]);
    #pragma unroll
    for (int q = 0; q < B_ROWS / 1024; ++q) p += pos[t + q * 1024];
    #pragma unroll
    for (int off = 1; off < 64; off <<= 1) {
        l += __shfl_xor(l, off);
        p += __shfl_xor(p, off);
    }
    __shared__ float red[2][16];
    if ((t & 63) == 0) { red[0][t >> 6] = l; red[1][t >> 6] = p; }
    __syncthreads();
    if (t == 0) {
        float L = 0.0f, P = 0.0f;
        #pragma unroll
        for (int q = 0; q < 16; ++q) { L += red[0][q]; P += red[1][q]; }
        out[0] = (L - P) * (1.0f / (float)N_ROWS);
    }
}

extern "C" void kernel_launch(void* const* d_in, const int* in_sizes, int n_in,
                              void* d_out, int out_size, void* d_ws, size_t ws_size,
                              hipStream_t stream) {
    (void)in_sizes; (void)n_in; (void)out_size; (void)ws_size;
    const float* zi = (const float*)d_in[0];
    const float* zj = (const float*)d_in[1];

    // workspace layout
    const size_t ZN_BYTES = (size_t)N_ROWS * D_DIM;  // 4 MiB fp8 (hc-tiled)
    unsigned char* Zn     = (unsigned char*)d_ws;
    float* rowsum_g       = (float*)((char*)d_ws + ZN_BYTES);              // 8192 f32
    float* pos            = (float*)((char*)d_ws + ZN_BYTES + N_ROWS * 4); // 4096 f32

    k_normalize<<<B_ROWS / 4, 256, 0, stream>>>(zi, zj, Zn, pos, rowsum_g);
    k_gemm_lse<<<NBLK, 256, 0, stream>>>(Zn, rowsum_g);
    k_finalize<<<1, 1024, 0, stream>>>(rowsum_g, pos, (float*)d_out);
}